// Round 1
// 393.491 us; speedup vs baseline: 1.4972x; 1.4972x over previous
//
#include <hip/hip_runtime.h>
#include <stdint.h>

// Problem constants (fixed by the reference)
#define CC   21        // n_classes
#define HWp  262144    // H*W = 512*512 (power of two: 2^18)
#define NPIX 2097152   // B*H*W = 8*512*512
#define PAD  257       // stage row stride in floats; 257 % 32 == 1 -> conflict-free both phases

// post_i = p_i * (CM . c)_i / sum_i p_i * (CM . c)_i
// (row-normalizations of p and c cancel in the final normalization)
//
// One pixel per thread. Inputs are read as scalar plane loads (lane-consecutive,
// 256B/wave-inst, fully coalesced). Output is transposed through LDS so global
// stores are lane-consecutive too (the old 336B-stride-per-lane float4 epilogue
// caused 3.36x write amplification + read-allocate fetch overhead).
__global__ __launch_bounds__(256, 6)
void ep_kernel(const float* __restrict__ prior,
               const float* __restrict__ current,
               const float* __restrict__ cm,
               float* __restrict__ out)
{
    // cmT[j*CC + i] = CM[i][j]; reads in the main loop are wave-uniform broadcasts
    __shared__ float cmT[CC * CC];
    // stage[i*PAD + t]: final output value for (pixel t of block, channel i)
    __shared__ float stage[CC * PAD];

    const int tid = threadIdx.x;
    for (int k = tid; k < CC * CC; k += 256) {
        int j = k / CC, i = k - j * CC;
        cmT[k] = cm[i * CC + j];
    }
    __syncthreads();

    const int n0   = blockIdx.x * 256 + tid;   // pixel index, one per thread
    const int b    = n0 >> 18;                 // n0 / HWp
    const int hw   = n0 & (HWp - 1);
    const int base = b * (CC << 18) + hw;      // + c*HWp per channel; max 44M, fits int

    float q[CC];
#pragma unroll
    for (int i = 0; i < CC; i++) q[i] = 0.f;

    // Pass 1: stream `current` planes, accumulate pred_i = sum_j CM[i][j]*c_j
#pragma unroll
    for (int j = 0; j < CC; j++) {
        float c = current[base + j * HWp];     // lane-consecutive scalar load
        const float* w = &cmT[j * CC];         // broadcast, conflict-free
#pragma unroll
        for (int i = 0; i < CC; i++) q[i] = fmaf(w[i], c, q[i]);
    }

    // Pass 2: stream `prior`, multiply in, accumulate the per-pixel normalizer
    float s = 0.f;
#pragma unroll
    for (int i = 0; i < CC; i++) {
        float p = prior[base + i * HWp];
        q[i] *= p;
        s += q[i];
    }
    const float r = 1.f / s;

    // Stage normalized values: lanes write consecutive addresses per channel row
    // (bank = (i*257 + tid) % 32 -> consecutive across lanes: conflict-free)
#pragma unroll
    for (int i = 0; i < CC; i++) stage[i * PAD + tid] = q[i] * r;
    __syncthreads();

    // Coalesced copy-out: this block owns 256*21 = 5376 contiguous output floats.
    // Wave stores 64 consecutive floats per instruction -> full cache lines only.
    const int bb = blockIdx.x * (256 * CC);    // max 44,035,... fits int
#pragma unroll
    for (int it = 0; it < CC; it++) {
        int m = it * 256 + tid;                // local output float index
        int t = m / CC;                        // magic-mul div by 21
        int i = m - t * CC;
        out[bb + m] = stage[i * PAD + t];      // read bank = (i+t)%32: <=3-way
    }
}

extern "C" void kernel_launch(void* const* d_in, const int* in_sizes, int n_in,
                              void* d_out, int out_size, void* d_ws, size_t ws_size,
                              hipStream_t stream) {
    const float* prior   = (const float*)d_in[0];
    const float* current = (const float*)d_in[1];
    const float* cm      = (const float*)d_in[2];
    float* out           = (float*)d_out;

    dim3 grid(NPIX / 256), block(256);         // 8192 blocks, 1 px/thread
    ep_kernel<<<grid, block, 0, stream>>>(prior, current, cm, out);
}